// Round 6
// baseline (772.957 us; speedup 1.0000x reference)
//
#include <hip/hip_runtime.h>
#include <hip/hip_fp16.h>
#include <cstdint>
#include <cstddef>

#define N_NODES 100000
#define N_EDGES 1600000
#define BSHIFT 9
#define BSIZE (1 << BSHIFT)
#define NB ((N_NODES + BSIZE - 1) >> BSHIFT)   // 196 buckets
#define PTILE 4096

#define NSLICE 8
#define SLICE_STRIDE ((size_t)N_NODES * 16)    // halfs per channel-slice

typedef _Float16 half8 __attribute__((ext_vector_type(8)));
typedef float floatx4 __attribute__((ext_vector_type(4)));

// ---------------------------------------------------------------------------
// edge_index dtype handling (int64 vs int32 delivered by JAX)
// ---------------------------------------------------------------------------
static __device__ __forceinline__ int edge_row(const void* ei, int i64, int e) {
    return i64 ? (int)((const long long*)ei)[e] : ((const int*)ei)[e];
}
static __device__ __forceinline__ int edge_col(const void* ei, int i64, int e) {
    return i64 ? (int)((const long long*)ei)[N_EDGES + e] : ((const int*)ei)[N_EDGES + e];
}

// widened (1024 thr) + folds bsize zeroing
__global__ void __launch_bounds__(1024)
detect_i64(const int* __restrict__ w, int* __restrict__ flag,
           int* __restrict__ bsize) {
    __shared__ int red[1024];
    const int tid = threadIdx.x;
    if (tid < NB + 1) bsize[tid] = 0;
    int acc = 0;
    for (int j = tid; j < 2048; j += 1024) {
        int k = j * 781;
        acc |= w[2 * k + 1];
    }
    red[tid] = acc;
    __syncthreads();
    for (int off = 512; off > 0; off >>= 1) {
        if (tid < off) red[tid] |= red[tid + off];
        __syncthreads();
    }
    if (tid == 0) *flag = (red[0] == 0) ? 1 : 0;
}

// per-tile LDS histogram of buckets -> few global atomics (196/block)
__global__ void __launch_bounds__(256)
hist_buckets(const void* __restrict__ ei, const int* __restrict__ flag,
             int* __restrict__ bsize) {
    __shared__ int h[256];
    const int tid = threadIdx.x;
    const int tbase = blockIdx.x * PTILE;
    const int f = *flag;
    h[tid] = 0;
    __syncthreads();
    #pragma unroll
    for (int j = 0; j < PTILE / 256; ++j) {
        int idx = tbase + tid + j * 256;
        if (idx < N_EDGES) {
            int r = edge_row(ei, f, idx);
            atomicAdd(&h[r >> BSHIFT], 1);
        }
    }
    __syncthreads();
    if (tid < NB && h[tid] > 0) atomicAdd(&bsize[tid], h[tid]);
}

// exclusive scan of bucket sizes -> bbase[NB+1], bcur
__global__ void scan_buckets(const int* __restrict__ bsize, int* __restrict__ bbase,
                             int* __restrict__ bcur) {
    __shared__ int sd[256];
    int t = threadIdx.x;
    int v = (t < NB) ? bsize[t] : 0;
    sd[t] = v;
    __syncthreads();
    for (int off = 1; off < 256; off <<= 1) {
        int add = (t >= off) ? sd[t - off] : 0;
        __syncthreads();
        sd[t] += add;
        __syncthreads();
    }
    if (t < NB) {
        bbase[t] = sd[t] - v;
        bcur[t] = sd[t] - v;
    }
    if (t == 255) bbase[NB] = sd[255];   // == N_EDGES
}

// partition edges into buckets (rows+cols planar, coalesced flush)
__global__ void __launch_bounds__(256)
partition_edges(const void* __restrict__ ei, const int* __restrict__ flag,
                int* __restrict__ bcur, int* __restrict__ bktRow,
                int* __restrict__ bktCol) {
    __shared__ int rows[PTILE];
    __shared__ int cols[PTILE];
    __shared__ int h[256], sc[256], exs[256], base_s[256], p[256];

    const int tid = threadIdx.x;
    const int tbase = blockIdx.x * PTILE;
    const int tot = min(PTILE, N_EDGES - tbase);
    const int f = *flag;

    h[tid] = 0;
    p[tid] = 0;
    __syncthreads();

    #pragma unroll
    for (int j = 0; j < PTILE / 256; ++j) {
        int idx = tbase + tid + j * 256;
        if (idx < N_EDGES) {
            int r = edge_row(ei, f, idx);
            atomicAdd(&h[r >> BSHIFT], 1);
        }
    }
    __syncthreads();

    sc[tid] = h[tid];
    __syncthreads();
    for (int off = 1; off < 256; off <<= 1) {
        int v = (tid >= off) ? sc[tid - off] : 0;
        __syncthreads();
        sc[tid] += v;
        __syncthreads();
    }
    exs[tid] = sc[tid] - h[tid];
    if (tid < NB && h[tid] > 0) base_s[tid] = atomicAdd(&bcur[tid], h[tid]);
    __syncthreads();

    #pragma unroll
    for (int j = 0; j < PTILE / 256; ++j) {
        int idx = tbase + tid + j * 256;
        if (idx < N_EDGES) {
            int r = edge_row(ei, f, idx);
            int c = edge_col(ei, f, idx);
            int b = r >> BSHIFT;
            int lp = atomicAdd(&p[b], 1);
            int slot = exs[b] + lp;
            rows[slot] = r;
            cols[slot] = c;
        }
    }
    __syncthreads();

    for (int slot = tid; slot < tot; slot += 256) {
        int r = rows[slot];
        int b = r >> BSHIFT;
        int addr = base_s[b] + (slot - exs[b]);
        bktRow[addr] = r;
        bktCol[addr] = cols[slot];
    }
}

// per-bucket: degree histogram (LDS) + local scan -> deg, rowst (coalesced)
// compute_dis folded in.
__global__ void __launch_bounds__(512)
bucket_stats(const int* __restrict__ bktRow, const int* __restrict__ bbase,
             int* __restrict__ deg, int* __restrict__ rowst,
             float* __restrict__ dis) {
    __shared__ int cnt[512];
    __shared__ int sd[512];
    const int b = blockIdx.x;
    const int t = threadIdx.x;
    const int start = bbase[b], end = bbase[b + 1];
    cnt[t] = 0;
    __syncthreads();
    for (int i = start + t; i < end; i += 512)
        atomicAdd(&cnt[bktRow[i] - (b << BSHIFT)], 1);
    __syncthreads();
    int v = cnt[t];
    sd[t] = v;
    __syncthreads();
    for (int off = 1; off < 512; off <<= 1) {
        int add = (t >= off) ? sd[t - off] : 0;
        __syncthreads();
        sd[t] += add;
        __syncthreads();
    }
    int node = (b << BSHIFT) + t;
    if (node < N_NODES) {
        deg[node] = v;
        rowst[node] = start + sd[t] - v;
        dis[node] = rsqrtf((float)v + 1.0f);
    }
}

// per-bucket scatter to final CSR with LDS cursors; nrm computed here
__global__ void __launch_bounds__(512)
scatter_bucket(const int* __restrict__ bktRow, const int* __restrict__ bktCol,
               const int* __restrict__ bbase, const int* __restrict__ rowst,
               const float* __restrict__ dis, int2* __restrict__ csr_cn) {
    __shared__ int cur[512];
    __shared__ float dl[512];
    const int b = blockIdx.x;
    const int t = threadIdx.x;
    const int start = bbase[b], end = bbase[b + 1];
    int node = (b << BSHIFT) + t;
    cur[t] = (node < N_NODES) ? rowst[node] : 0;
    dl[t]  = (node < N_NODES) ? dis[node] : 0.f;
    __syncthreads();
    for (int i = start + t; i < end; i += 512) {
        int r = bktRow[i];
        int c = bktCol[i];
        int lr = r - (b << BSHIFT);
        int pos = atomicAdd(&cur[lr], 1);
        float nrm = dl[lr] * dis[c];
        csr_cn[pos] = make_int2(c, __float_as_int(nrm));
    }
}

// ---------------------------------------------------------------------------
// MFMA GEMM with XOR-swizzled LDS B tile.
// SIN:  A read from channel-sliced layout [8][N][16] halfs (fp16 only).
// SOUT: C written to channel-sliced layout (requires NT=8, Mfull=128;
//       slice == ct, within-slice channel == m).
// ---------------------------------------------------------------------------
template<typename TIn, int NT, bool SIN, bool SOUT>
__global__ void __launch_bounds__(256)
gemm_mfma(const TIn* __restrict__ in, const float* __restrict__ W,
          __half* __restrict__ out, int Mfull, int ostride) {
    constexpr int NCOL = NT * 16;
    __shared__ _Float16 Wt[NCOL * 128];

    const int tid = threadIdx.x;
    for (int chunkIdx = tid; chunkIdx < NCOL * 16; chunkIdx += 256) {
        int n = chunkIdx % NCOL;
        int c = chunkIdx / NCOL;
        half8 v;
        #pragma unroll
        for (int i = 0; i < 8; ++i) {
            int k = c * 8 + i;
            v[i] = (n < Mfull) ? (_Float16)W[k * Mfull + n] : (_Float16)0.f;
        }
        *(half8*)&Wt[n * 128 + (c ^ (n & 7)) * 8] = v;
    }
    __syncthreads();

    const int wave = tid >> 6, lane = tid & 63;
    const int quad = lane >> 4, m = lane & 15;
    const int rowbase = blockIdx.x * 64 + wave * 16;
    const int arow_i = rowbase + m;
    const int arow_cl = (arow_i < N_NODES) ? arow_i : 0;

    half8 a[4];
    #pragma unroll
    for (int kt = 0; kt < 4; ++kt) {
        if constexpr (SIN) {
            // channels [kt*32+quad*8, +8) all lie in slice kt*2 + (quad>>1)
            int sc = kt * 2 + (quad >> 1);
            const _Float16* src = (const _Float16*)in
                + (size_t)sc * SLICE_STRIDE + (size_t)arow_cl * 16 + (quad & 1) * 8;
            a[kt] = *(const half8*)src;
        } else if constexpr (sizeof(TIn) == 4) {
            const float* arow = (const float*)in + (size_t)arow_cl * 128;
            const float4* ptr = (const float4*)(arow + kt * 32 + quad * 8);
            float4 f0 = ptr[0];
            float4 f1 = ptr[1];
            a[kt][0] = (_Float16)f0.x; a[kt][1] = (_Float16)f0.y;
            a[kt][2] = (_Float16)f0.z; a[kt][3] = (_Float16)f0.w;
            a[kt][4] = (_Float16)f1.x; a[kt][5] = (_Float16)f1.y;
            a[kt][6] = (_Float16)f1.z; a[kt][7] = (_Float16)f1.w;
        } else {
            const _Float16* arow = (const _Float16*)in + (size_t)arow_cl * 128;
            a[kt] = *(const half8*)(arow + kt * 32 + quad * 8);
        }
    }

    floatx4 acc[NT];
    #pragma unroll
    for (int ct = 0; ct < NT; ++ct) acc[ct] = (floatx4){0.f, 0.f, 0.f, 0.f};

    #pragma unroll
    for (int ct = 0; ct < NT; ++ct) {
        #pragma unroll
        for (int kt = 0; kt < 4; ++kt) {
            int n = ct * 16 + m;
            half8 bfrag = *(const half8*)&Wt[n * 128 + ((kt * 4 + quad) ^ (m & 7)) * 8];
            acc[ct] = __builtin_amdgcn_mfma_f32_16x16x32_f16(a[kt], bfrag, acc[ct], 0, 0, 0);
        }
    }

    const int rs0 = rowbase + quad * 4;
    #pragma unroll
    for (int ct = 0; ct < NT; ++ct) {
        int col = ct * 16 + m;
        if (col >= Mfull) continue;
        #pragma unroll
        for (int r = 0; r < 4; ++r) {
            int rs = rs0 + r;
            if (rs < N_NODES) {
                if constexpr (SOUT)
                    out[(size_t)ct * SLICE_STRIDE + (size_t)rs * 16 + m] =
                        __float2half(acc[ct][r]);
                else
                    out[(size_t)rs * ostride + col] = __float2half(acc[ct][r]);
            }
        }
    }
}

// ---------------------------------------------------------------------------
// XCD-sliced CSR aggregation. slice = blockIdx & 7 (round-robin -> XCD);
// each slice gathers only its 16 channels (32 B/row, 3.2 MB table: fits the
// XCD's 4 MB L2). Wave = 8 edge-groups x 8 channel-pair lanes; shfl_xor
// combine; lanes 0-7 write the 32-B sliced output row.
// ---------------------------------------------------------------------------
__global__ void __launch_bounds__(256)
agg_c128_sl(const __half* __restrict__ ts, const int* __restrict__ rowst,
            const int* __restrict__ deg, const int2* __restrict__ cn,
            const float* __restrict__ dis, const float* __restrict__ bias,
            __half* __restrict__ outs, int relu) {
    const int slice = blockIdx.x & 7;
    const int sblk  = blockIdx.x >> 3;
    const int nsb   = gridDim.x >> 3;
    const int wave  = threadIdx.x >> 6;
    const int lane  = threadIdx.x & 63;
    const int g     = lane >> 3;          // edge group 0..7
    const int p     = lane & 7;           // channel pair 0..7
    const __half* tsl = ts + (size_t)slice * SLICE_STRIDE;
    __half* osl = outs + (size_t)slice * SLICE_STRIDE;
    const float2 bv = *(const float2*)(bias + slice * 16 + p * 2);

    for (int w = sblk * 4 + wave; w < N_NODES; w += nsb * 4) {
        int s = rowst[w], d = deg[w];
        float di = dis[w], sn = di * di;
        float ax = 0.f, ay = 0.f;
        if (g == 0) {
            float2 tv = __half22float2(*(const __half2*)(tsl + (size_t)w * 16 + p * 2));
            ax = sn * tv.x; ay = sn * tv.y;
        }
        int e = s + d;
        int rounds = (d + 7) >> 3;
        int j = s + g;
        for (int r = 0; r < rounds; ++r, j += 8) {
            bool act = j < e;
            int2 c = act ? cn[j] : make_int2(0, 0);
            float2 fv = __half22float2(
                *(const __half2*)(tsl + (size_t)c.x * 16 + p * 2));
            float nw = __int_as_float(c.y);     // 0.0f when masked
            ax = fmaf(nw, fv.x, ax);
            ay = fmaf(nw, fv.y, ay);
        }
        ax += __shfl_xor(ax, 8);  ay += __shfl_xor(ay, 8);
        ax += __shfl_xor(ax, 16); ay += __shfl_xor(ay, 16);
        ax += __shfl_xor(ax, 32); ay += __shfl_xor(ay, 32);
        if (g == 0) {
            ax += bv.x; ay += bv.y;
            if (relu) { ax = fmaxf(ax, 0.f); ay = fmaxf(ay, 0.f); }
            *(__half2*)(osl + (size_t)w * 16 + p * 2) =
                __float22half2_rn(make_float2(ax, ay));
        }
    }
}

// ---------------------------------------------------------------------------
// agg_c47 (proven R5 version): t rows padded to 64 halves, dual-edge
// half-waves, rolling-4 pipeline, shfl_xor(32) combine.
// ---------------------------------------------------------------------------
#define C47_DEPTH 4
#define AGG_BLOCKS 2048

__global__ void __launch_bounds__(256)
agg_c47(const __half* __restrict__ t, const int* __restrict__ rowst,
        const int* __restrict__ deg, const int2* __restrict__ cn,
        const float* __restrict__ dis, const float* __restrict__ bias,
        float* __restrict__ out) {
    const int gwave = blockIdx.x * (blockDim.x >> 6) + (threadIdx.x >> 6);
    const int nw = gridDim.x * (blockDim.x >> 6);
    const int lane = threadIdx.x & 63;
    const int hw = lane >> 5;
    const int l2 = lane & 31;
    const int ch0 = l2 * 2, ch1 = ch0 + 1;
    const float b0 = (ch0 < 47) ? bias[ch0] : 0.f;
    const float b1 = (ch1 < 47) ? bias[ch1] : 0.f;

    for (int w = gwave; w < N_NODES; w += nw) {
        int s = rowst[w], d = deg[w];
        float di = dis[w];
        float sn = di * di;
        float2 tv = __half22float2(((const __half2*)(t + (size_t)w * 64))[l2]);
        float ax = (hw == 0) ? sn * tv.x : 0.f;
        float ay = (hw == 0) ? sn * tv.y : 0.f;
        int e = s + d;
        int j = s + hw;
        if (j + 2 * C47_DEPTH <= e + 1) {
            int2 c[C47_DEPTH];
            #pragma unroll
            for (int q = 0; q < C47_DEPTH; ++q) c[q] = cn[j + 2 * q];
            j += 2 * C47_DEPTH;
            while (j + 2 * C47_DEPTH <= e + 1) {
                int2 n[C47_DEPTH];
                #pragma unroll
                for (int q = 0; q < C47_DEPTH; ++q) n[q] = cn[j + 2 * q];
                __half2 v[C47_DEPTH];
                #pragma unroll
                for (int q = 0; q < C47_DEPTH; ++q)
                    v[q] = ((const __half2*)(t + (size_t)c[q].x * 64))[l2];
                #pragma unroll
                for (int q = 0; q < C47_DEPTH; ++q) {
                    float2 fv = __half22float2(v[q]);
                    float nw2 = __int_as_float(c[q].y);
                    ax = fmaf(nw2, fv.x, ax);
                    ay = fmaf(nw2, fv.y, ay);
                }
                #pragma unroll
                for (int q = 0; q < C47_DEPTH; ++q) c[q] = n[q];
                j += 2 * C47_DEPTH;
            }
            #pragma unroll
            for (int q = 0; q < C47_DEPTH; ++q) {
                __half2 vv = ((const __half2*)(t + (size_t)c[q].x * 64))[l2];
                float2 fv = __half22float2(vv);
                float nw2 = __int_as_float(c[q].y);
                ax = fmaf(nw2, fv.x, ax);
                ay = fmaf(nw2, fv.y, ay);
            }
        }
        for (; j < e; j += 2) {
            int2 c = cn[j];
            float2 fv = __half22float2(((const __half2*)(t + (size_t)c.x * 64))[l2]);
            float nw2 = __int_as_float(c.y);
            ax = fmaf(nw2, fv.x, ax);
            ay = fmaf(nw2, fv.y, ay);
        }
        ax += __shfl_xor(ax, 32);
        ay += __shfl_xor(ay, 32);
        if (hw == 0) {
            if (ch0 < 47) out[(size_t)w * 47 + ch0] = ax + b0;
            if (ch1 < 47) out[(size_t)w * 47 + ch1] = ay + b1;
        }
    }
}

// ---------------------------------------------------------------------------
extern "C" void kernel_launch(void* const* d_in, const int* in_sizes, int n_in,
                              void* d_out, int out_size, void* d_ws, size_t ws_size,
                              hipStream_t stream) {
    const float* x  = (const float*)d_in[0];
    const void*  ei = d_in[1];
    const float* W1 = (const float*)d_in[3];
    const float* b1 = (const float*)d_in[4];
    const float* W2 = (const float*)d_in[5];
    const float* b2 = (const float*)d_in[6];
    const float* W3 = (const float*)d_in[7];
    const float* b3 = (const float*)d_in[8];
    float* out = (float*)d_out;

    size_t off = 0;
    auto alloc = [&](size_t bytes) -> void* {
        void* p = (char*)d_ws + off;
        off += (bytes + 511) & ~(size_t)511;
        return p;
    };
    float*  dis     = (float*)alloc((size_t)N_NODES * 4);
    int*    deg     = (int*)  alloc((size_t)N_NODES * 4);
    int*    rowst   = (int*)  alloc((size_t)N_NODES * 4);
    int*    bsize   = (int*)  alloc((NB + 1) * 4);
    int*    bbase   = (int*)  alloc((NB + 1) * 4);
    int*    bcur    = (int*)  alloc(NB * 4);
    int*    flag    = (int*)  alloc(64);
    int2*   csr_cn  = (int2*) alloc((size_t)N_EDGES * 8);
    __half* tbuf    = (__half*)alloc((size_t)N_NODES * 128 * 2);  // sliced t [8][N][16]
    __half* hbuf    = (__half*)alloc((size_t)N_NODES * 128 * 2);  // sliced act [8][N][16]
    // bucket planar arrays alias hbuf (12.8MB < 25.6MB; dead before gemm1 output use)
    int*    bktRow  = (int*)hbuf;
    int*    bktCol  = bktRow + N_EDGES;
    // layer-3 t rows [N][64] alias tbuf (tbuf dead after agg2 reads it)
    __half* t3      = tbuf;
    (void)ws_size; (void)in_sizes; (void)n_in; (void)out_size;

    int ptiles = (N_EDGES + PTILE - 1) / PTILE;   // 391

    // --- preprocessing ---
    detect_i64<<<1, 1024, 0, stream>>>((const int*)ei, flag, bsize);
    hist_buckets<<<ptiles, 256, 0, stream>>>(ei, flag, bsize);
    scan_buckets<<<1, 256, 0, stream>>>(bsize, bbase, bcur);
    partition_edges<<<ptiles, 256, 0, stream>>>(ei, flag, bcur, bktRow, bktCol);
    bucket_stats<<<NB, 512, 0, stream>>>(bktRow, bbase, deg, rowst, dis);
    scatter_bucket<<<NB, 512, 0, stream>>>(bktRow, bktCol, bbase, rowst, dis, csr_cn);

    int gblocks = (N_NODES + 63) / 64;   // 1563

    // --- layer 1 (fp32 in, sliced out) ---
    gemm_mfma<float, 8, false, true><<<gblocks, 256, 0, stream>>>(x, W1, tbuf, 128, 0);
    agg_c128_sl<<<2048, 256, 0, stream>>>(tbuf, rowst, deg, csr_cn, dis, b1, hbuf, 1);
    // --- layer 2 (sliced in, sliced out) ---
    gemm_mfma<_Float16, 8, true, true><<<gblocks, 256, 0, stream>>>(
        (_Float16*)hbuf, W2, tbuf, 128, 0);
    agg_c128_sl<<<2048, 256, 0, stream>>>(tbuf, rowst, deg, csr_cn, dis, b2, hbuf, 1);
    // --- layer 3 (sliced in, 47 cols, rows padded to 64 halves) ---
    gemm_mfma<_Float16, 3, true, false><<<gblocks, 256, 0, stream>>>(
        (_Float16*)hbuf, W3, t3, 47, 64);
    agg_c47<<<AGG_BLOCKS, 256, 0, stream>>>(t3, rowst, deg, csr_cn, dis, b3, out);
}

// Round 7
// 772.629 us; speedup vs baseline: 1.0004x; 1.0004x over previous
//
#include <hip/hip_runtime.h>
#include <hip/hip_fp16.h>
#include <cstdint>
#include <cstddef>

#define N_NODES 100000
#define N_EDGES 1600000
#define BSHIFT 9
#define BSIZE (1 << BSHIFT)
#define NB ((N_NODES + BSIZE - 1) >> BSHIFT)   // 196 buckets
#define PTILE 4096

#define NSLICE 8
#define SLICE_STRIDE ((size_t)N_NODES * 16)    // halfs per channel-slice

typedef _Float16 half8 __attribute__((ext_vector_type(8)));
typedef float floatx4 __attribute__((ext_vector_type(4)));

// ---------------------------------------------------------------------------
// edge_index dtype handling (int64 vs int32 delivered by JAX)
// ---------------------------------------------------------------------------
static __device__ __forceinline__ int edge_row(const void* ei, int i64, int e) {
    return i64 ? (int)((const long long*)ei)[e] : ((const int*)ei)[e];
}
static __device__ __forceinline__ int edge_col(const void* ei, int i64, int e) {
    return i64 ? (int)((const long long*)ei)[N_EDGES + e] : ((const int*)ei)[N_EDGES + e];
}

// widened (1024 thr) + folds bsize zeroing
__global__ void __launch_bounds__(1024)
detect_i64(const int* __restrict__ w, int* __restrict__ flag,
           int* __restrict__ bsize) {
    __shared__ int red[1024];
    const int tid = threadIdx.x;
    if (tid < NB + 1) bsize[tid] = 0;
    int acc = 0;
    for (int j = tid; j < 2048; j += 1024) {
        int k = j * 781;
        acc |= w[2 * k + 1];
    }
    red[tid] = acc;
    __syncthreads();
    for (int off = 512; off > 0; off >>= 1) {
        if (tid < off) red[tid] |= red[tid + off];
        __syncthreads();
    }
    if (tid == 0) *flag = (red[0] == 0) ? 1 : 0;
}

// per-tile LDS histogram of buckets -> few global atomics (196/block)
__global__ void __launch_bounds__(256)
hist_buckets(const void* __restrict__ ei, const int* __restrict__ flag,
             int* __restrict__ bsize) {
    __shared__ int h[256];
    const int tid = threadIdx.x;
    const int tbase = blockIdx.x * PTILE;
    const int f = *flag;
    h[tid] = 0;
    __syncthreads();
    #pragma unroll
    for (int j = 0; j < PTILE / 256; ++j) {
        int idx = tbase + tid + j * 256;
        if (idx < N_EDGES) {
            int r = edge_row(ei, f, idx);
            atomicAdd(&h[r >> BSHIFT], 1);
        }
    }
    __syncthreads();
    if (tid < NB && h[tid] > 0) atomicAdd(&bsize[tid], h[tid]);
}

// exclusive scan of bucket sizes -> bbase[NB+1], bcur
__global__ void scan_buckets(const int* __restrict__ bsize, int* __restrict__ bbase,
                             int* __restrict__ bcur) {
    __shared__ int sd[256];
    int t = threadIdx.x;
    int v = (t < NB) ? bsize[t] : 0;
    sd[t] = v;
    __syncthreads();
    for (int off = 1; off < 256; off <<= 1) {
        int add = (t >= off) ? sd[t - off] : 0;
        __syncthreads();
        sd[t] += add;
        __syncthreads();
    }
    if (t < NB) {
        bbase[t] = sd[t] - v;
        bcur[t] = sd[t] - v;
    }
    if (t == 255) bbase[NB] = sd[255];   // == N_EDGES
}

// partition edges into buckets (rows+cols planar, coalesced flush)
__global__ void __launch_bounds__(256)
partition_edges(const void* __restrict__ ei, const int* __restrict__ flag,
                int* __restrict__ bcur, int* __restrict__ bktRow,
                int* __restrict__ bktCol) {
    __shared__ int rows[PTILE];
    __shared__ int cols[PTILE];
    __shared__ int h[256], sc[256], exs[256], base_s[256], p[256];

    const int tid = threadIdx.x;
    const int tbase = blockIdx.x * PTILE;
    const int tot = min(PTILE, N_EDGES - tbase);
    const int f = *flag;

    h[tid] = 0;
    p[tid] = 0;
    __syncthreads();

    #pragma unroll
    for (int j = 0; j < PTILE / 256; ++j) {
        int idx = tbase + tid + j * 256;
        if (idx < N_EDGES) {
            int r = edge_row(ei, f, idx);
            atomicAdd(&h[r >> BSHIFT], 1);
        }
    }
    __syncthreads();

    sc[tid] = h[tid];
    __syncthreads();
    for (int off = 1; off < 256; off <<= 1) {
        int v = (tid >= off) ? sc[tid - off] : 0;
        __syncthreads();
        sc[tid] += v;
        __syncthreads();
    }
    exs[tid] = sc[tid] - h[tid];
    if (tid < NB && h[tid] > 0) base_s[tid] = atomicAdd(&bcur[tid], h[tid]);
    __syncthreads();

    #pragma unroll
    for (int j = 0; j < PTILE / 256; ++j) {
        int idx = tbase + tid + j * 256;
        if (idx < N_EDGES) {
            int r = edge_row(ei, f, idx);
            int c = edge_col(ei, f, idx);
            int b = r >> BSHIFT;
            int lp = atomicAdd(&p[b], 1);
            int slot = exs[b] + lp;
            rows[slot] = r;
            cols[slot] = c;
        }
    }
    __syncthreads();

    for (int slot = tid; slot < tot; slot += 256) {
        int r = rows[slot];
        int b = r >> BSHIFT;
        int addr = base_s[b] + (slot - exs[b]);
        bktRow[addr] = r;
        bktCol[addr] = cols[slot];
    }
}

// per-bucket: degree histogram (LDS) + local scan -> deg, rowst (coalesced)
// compute_dis folded in.
__global__ void __launch_bounds__(512)
bucket_stats(const int* __restrict__ bktRow, const int* __restrict__ bbase,
             int* __restrict__ deg, int* __restrict__ rowst,
             float* __restrict__ dis) {
    __shared__ int cnt[512];
    __shared__ int sd[512];
    const int b = blockIdx.x;
    const int t = threadIdx.x;
    const int start = bbase[b], end = bbase[b + 1];
    cnt[t] = 0;
    __syncthreads();
    for (int i = start + t; i < end; i += 512)
        atomicAdd(&cnt[bktRow[i] - (b << BSHIFT)], 1);
    __syncthreads();
    int v = cnt[t];
    sd[t] = v;
    __syncthreads();
    for (int off = 1; off < 512; off <<= 1) {
        int add = (t >= off) ? sd[t - off] : 0;
        __syncthreads();
        sd[t] += add;
        __syncthreads();
    }
    int node = (b << BSHIFT) + t;
    if (node < N_NODES) {
        deg[node] = v;
        rowst[node] = start + sd[t] - v;
        dis[node] = rsqrtf((float)v + 1.0f);
    }
}

// per-bucket scatter to final CSR with LDS cursors; nrm computed here
__global__ void __launch_bounds__(512)
scatter_bucket(const int* __restrict__ bktRow, const int* __restrict__ bktCol,
               const int* __restrict__ bbase, const int* __restrict__ rowst,
               const float* __restrict__ dis, int2* __restrict__ csr_cn) {
    __shared__ int cur[512];
    __shared__ float dl[512];
    const int b = blockIdx.x;
    const int t = threadIdx.x;
    const int start = bbase[b], end = bbase[b + 1];
    int node = (b << BSHIFT) + t;
    cur[t] = (node < N_NODES) ? rowst[node] : 0;
    dl[t]  = (node < N_NODES) ? dis[node] : 0.f;
    __syncthreads();
    for (int i = start + t; i < end; i += 512) {
        int r = bktRow[i];
        int c = bktCol[i];
        int lr = r - (b << BSHIFT);
        int pos = atomicAdd(&cur[lr], 1);
        float nrm = dl[lr] * dis[c];
        csr_cn[pos] = make_int2(c, __float_as_int(nrm));
    }
}

// ---------------------------------------------------------------------------
// MFMA GEMM with XOR-swizzled LDS B tile.
// SIN:  A read from channel-sliced layout [8][N][16] halfs (fp16 only).
// SOUT: C written to channel-sliced layout (requires NT=8, Mfull=128).
// ---------------------------------------------------------------------------
template<typename TIn, int NT, bool SIN, bool SOUT>
__global__ void __launch_bounds__(256)
gemm_mfma(const TIn* __restrict__ in, const float* __restrict__ W,
          __half* __restrict__ out, int Mfull, int ostride) {
    constexpr int NCOL = NT * 16;
    __shared__ _Float16 Wt[NCOL * 128];

    const int tid = threadIdx.x;
    for (int chunkIdx = tid; chunkIdx < NCOL * 16; chunkIdx += 256) {
        int n = chunkIdx % NCOL;
        int c = chunkIdx / NCOL;
        half8 v;
        #pragma unroll
        for (int i = 0; i < 8; ++i) {
            int k = c * 8 + i;
            v[i] = (n < Mfull) ? (_Float16)W[k * Mfull + n] : (_Float16)0.f;
        }
        *(half8*)&Wt[n * 128 + (c ^ (n & 7)) * 8] = v;
    }
    __syncthreads();

    const int wave = tid >> 6, lane = tid & 63;
    const int quad = lane >> 4, m = lane & 15;
    const int rowbase = blockIdx.x * 64 + wave * 16;
    const int arow_i = rowbase + m;
    const int arow_cl = (arow_i < N_NODES) ? arow_i : 0;

    half8 a[4];
    #pragma unroll
    for (int kt = 0; kt < 4; ++kt) {
        if constexpr (SIN) {
            // channels [kt*32+quad*8, +8) all lie in slice kt*2 + (quad>>1)
            int sc = kt * 2 + (quad >> 1);
            const _Float16* src = (const _Float16*)in
                + (size_t)sc * SLICE_STRIDE + (size_t)arow_cl * 16 + (quad & 1) * 8;
            a[kt] = *(const half8*)src;
        } else if constexpr (sizeof(TIn) == 4) {
            const float* arow = (const float*)in + (size_t)arow_cl * 128;
            const float4* ptr = (const float4*)(arow + kt * 32 + quad * 8);
            float4 f0 = ptr[0];
            float4 f1 = ptr[1];
            a[kt][0] = (_Float16)f0.x; a[kt][1] = (_Float16)f0.y;
            a[kt][2] = (_Float16)f0.z; a[kt][3] = (_Float16)f0.w;
            a[kt][4] = (_Float16)f1.x; a[kt][5] = (_Float16)f1.y;
            a[kt][6] = (_Float16)f1.z; a[kt][7] = (_Float16)f1.w;
        } else {
            const _Float16* arow = (const _Float16*)in + (size_t)arow_cl * 128;
            a[kt] = *(const half8*)(arow + kt * 32 + quad * 8);
        }
    }

    floatx4 acc[NT];
    #pragma unroll
    for (int ct = 0; ct < NT; ++ct) acc[ct] = (floatx4){0.f, 0.f, 0.f, 0.f};

    #pragma unroll
    for (int ct = 0; ct < NT; ++ct) {
        #pragma unroll
        for (int kt = 0; kt < 4; ++kt) {
            int n = ct * 16 + m;
            half8 bfrag = *(const half8*)&Wt[n * 128 + ((kt * 4 + quad) ^ (m & 7)) * 8];
            acc[ct] = __builtin_amdgcn_mfma_f32_16x16x32_f16(a[kt], bfrag, acc[ct], 0, 0, 0);
        }
    }

    const int rs0 = rowbase + quad * 4;
    #pragma unroll
    for (int ct = 0; ct < NT; ++ct) {
        int col = ct * 16 + m;
        if (col >= Mfull) continue;
        #pragma unroll
        for (int r = 0; r < 4; ++r) {
            int rs = rs0 + r;
            if (rs < N_NODES) {
                if constexpr (SOUT)
                    out[(size_t)ct * SLICE_STRIDE + (size_t)rs * 16 + m] =
                        __float2half(acc[ct][r]);
                else
                    out[(size_t)rs * ostride + col] = __float2half(acc[ct][r]);
            }
        }
    }
}

// ---------------------------------------------------------------------------
// XCD-sliced CSR aggregation v2: dual-node, masked batch-4 rounds.
// slice = blockIdx & 7 (round-robin -> XCD). Per wave iteration: 2 nodes in
// lockstep, 8 independent cn loads + 8 independent gathers in flight (32
// lines) before any FMA — restores the MLP the v1 rounds-loop lost.
// Masked slots gather row 0 with weight 0 (hot L2 line, free).
// cn loads + output stores are nontemporal: protect the 3.2 MB table's L2
// residency from the streaming traffic.
// ---------------------------------------------------------------------------
__global__ void __launch_bounds__(256)
agg_c128_sl(const __half* __restrict__ ts, const int* __restrict__ rowst,
            const int* __restrict__ deg, const int2* __restrict__ cn,
            const float* __restrict__ dis, const float* __restrict__ bias,
            __half* __restrict__ outs, int relu) {
    const int slice = blockIdx.x & 7;
    const int sblk  = blockIdx.x >> 3;
    const int nsb   = gridDim.x >> 3;
    const int wave  = threadIdx.x >> 6;
    const int lane  = threadIdx.x & 63;
    const int g     = lane >> 3;          // edge group 0..7
    const int p     = lane & 7;           // channel pair 0..7
    const __half* tsl = ts + (size_t)slice * SLICE_STRIDE;
    __half* osl = outs + (size_t)slice * SLICE_STRIDE;
    const float2 bv = *(const float2*)(bias + slice * 16 + p * 2);
    const long long* cn8 = (const long long*)cn;
    const int wstride = nsb * 4;

    for (int w0 = sblk * 4 + wave; w0 < N_NODES; w0 += 2 * wstride) {
        const int w1 = w0 + wstride;
        const bool h1 = w1 < N_NODES;
        int s0 = rowst[w0], d0 = deg[w0];
        float di0 = dis[w0], sn0 = di0 * di0;
        int s1 = h1 ? rowst[w1] : 0, d1 = h1 ? deg[w1] : 0;
        float di1 = h1 ? dis[w1] : 0.f, sn1 = di1 * di1;
        float ax0 = 0.f, ay0 = 0.f, ax1 = 0.f, ay1 = 0.f;
        if (g == 0) {
            float2 tv0 = __half22float2(*(const __half2*)(tsl + (size_t)w0 * 16 + p * 2));
            ax0 = sn0 * tv0.x; ay0 = sn0 * tv0.y;
            if (h1) {
                float2 tv1 = __half22float2(*(const __half2*)(tsl + (size_t)w1 * 16 + p * 2));
                ax1 = sn1 * tv1.x; ay1 = sn1 * tv1.y;
            }
        }
        const int e0 = s0 + d0, e1 = s1 + d1;
        int j0 = s0 + g, j1 = s1 + g;
        while (j0 < e0 || j1 < e1) {
            long long c0[4], c1[4];
            #pragma unroll
            for (int q = 0; q < 4; ++q) {
                int jj = j0 + 8 * q;
                c0[q] = (jj < e0) ? __builtin_nontemporal_load(cn8 + jj) : 0LL;
            }
            #pragma unroll
            for (int q = 0; q < 4; ++q) {
                int jj = j1 + 8 * q;
                c1[q] = (jj < e1) ? __builtin_nontemporal_load(cn8 + jj) : 0LL;
            }
            __half2 v0[4], v1[4];
            #pragma unroll
            for (int q = 0; q < 4; ++q)
                v0[q] = *(const __half2*)(tsl + (size_t)(unsigned)(int)c0[q] * 16 + p * 2);
            #pragma unroll
            for (int q = 0; q < 4; ++q)
                v1[q] = *(const __half2*)(tsl + (size_t)(unsigned)(int)c1[q] * 16 + p * 2);
            #pragma unroll
            for (int q = 0; q < 4; ++q) {
                float2 fv = __half22float2(v0[q]);
                float nw = __int_as_float((int)(c0[q] >> 32));
                ax0 = fmaf(nw, fv.x, ax0);
                ay0 = fmaf(nw, fv.y, ay0);
            }
            #pragma unroll
            for (int q = 0; q < 4; ++q) {
                float2 fv = __half22float2(v1[q]);
                float nw = __int_as_float((int)(c1[q] >> 32));
                ax1 = fmaf(nw, fv.x, ax1);
                ay1 = fmaf(nw, fv.y, ay1);
            }
            j0 += 32; j1 += 32;
        }
        ax0 += __shfl_xor(ax0, 8);  ay0 += __shfl_xor(ay0, 8);
        ax0 += __shfl_xor(ax0, 16); ay0 += __shfl_xor(ay0, 16);
        ax0 += __shfl_xor(ax0, 32); ay0 += __shfl_xor(ay0, 32);
        ax1 += __shfl_xor(ax1, 8);  ay1 += __shfl_xor(ay1, 8);
        ax1 += __shfl_xor(ax1, 16); ay1 += __shfl_xor(ay1, 16);
        ax1 += __shfl_xor(ax1, 32); ay1 += __shfl_xor(ay1, 32);
        if (g == 0) {
            float rx0 = ax0 + bv.x, ry0 = ay0 + bv.y;
            if (relu) { rx0 = fmaxf(rx0, 0.f); ry0 = fmaxf(ry0, 0.f); }
            __half2 hv0 = __float22half2_rn(make_float2(rx0, ry0));
            __builtin_nontemporal_store(*(unsigned int*)&hv0,
                (unsigned int*)(osl + (size_t)w0 * 16 + p * 2));
            if (h1) {
                float rx1 = ax1 + bv.x, ry1 = ay1 + bv.y;
                if (relu) { rx1 = fmaxf(rx1, 0.f); ry1 = fmaxf(ry1, 0.f); }
                __half2 hv1 = __float22half2_rn(make_float2(rx1, ry1));
                __builtin_nontemporal_store(*(unsigned int*)&hv1,
                    (unsigned int*)(osl + (size_t)w1 * 16 + p * 2));
            }
        }
    }
}

// ---------------------------------------------------------------------------
// agg_c47 (proven R5 version): t rows padded to 64 halves, dual-edge
// half-waves, rolling-4 pipeline, shfl_xor(32) combine.
// ---------------------------------------------------------------------------
#define C47_DEPTH 4
#define AGG_BLOCKS 2048

__global__ void __launch_bounds__(256)
agg_c47(const __half* __restrict__ t, const int* __restrict__ rowst,
        const int* __restrict__ deg, const int2* __restrict__ cn,
        const float* __restrict__ dis, const float* __restrict__ bias,
        float* __restrict__ out) {
    const int gwave = blockIdx.x * (blockDim.x >> 6) + (threadIdx.x >> 6);
    const int nw = gridDim.x * (blockDim.x >> 6);
    const int lane = threadIdx.x & 63;
    const int hw = lane >> 5;
    const int l2 = lane & 31;
    const int ch0 = l2 * 2, ch1 = ch0 + 1;
    const float b0 = (ch0 < 47) ? bias[ch0] : 0.f;
    const float b1 = (ch1 < 47) ? bias[ch1] : 0.f;

    for (int w = gwave; w < N_NODES; w += nw) {
        int s = rowst[w], d = deg[w];
        float di = dis[w];
        float sn = di * di;
        float2 tv = __half22float2(((const __half2*)(t + (size_t)w * 64))[l2]);
        float ax = (hw == 0) ? sn * tv.x : 0.f;
        float ay = (hw == 0) ? sn * tv.y : 0.f;
        int e = s + d;
        int j = s + hw;
        if (j + 2 * C47_DEPTH <= e + 1) {
            int2 c[C47_DEPTH];
            #pragma unroll
            for (int q = 0; q < C47_DEPTH; ++q) c[q] = cn[j + 2 * q];
            j += 2 * C47_DEPTH;
            while (j + 2 * C47_DEPTH <= e + 1) {
                int2 n[C47_DEPTH];
                #pragma unroll
                for (int q = 0; q < C47_DEPTH; ++q) n[q] = cn[j + 2 * q];
                __half2 v[C47_DEPTH];
                #pragma unroll
                for (int q = 0; q < C47_DEPTH; ++q)
                    v[q] = ((const __half2*)(t + (size_t)c[q].x * 64))[l2];
                #pragma unroll
                for (int q = 0; q < C47_DEPTH; ++q) {
                    float2 fv = __half22float2(v[q]);
                    float nw2 = __int_as_float(c[q].y);
                    ax = fmaf(nw2, fv.x, ax);
                    ay = fmaf(nw2, fv.y, ay);
                }
                #pragma unroll
                for (int q = 0; q < C47_DEPTH; ++q) c[q] = n[q];
                j += 2 * C47_DEPTH;
            }
            #pragma unroll
            for (int q = 0; q < C47_DEPTH; ++q) {
                __half2 vv = ((const __half2*)(t + (size_t)c[q].x * 64))[l2];
                float2 fv = __half22float2(vv);
                float nw2 = __int_as_float(c[q].y);
                ax = fmaf(nw2, fv.x, ax);
                ay = fmaf(nw2, fv.y, ay);
            }
        }
        for (; j < e; j += 2) {
            int2 c = cn[j];
            float2 fv = __half22float2(((const __half2*)(t + (size_t)c.x * 64))[l2]);
            float nw2 = __int_as_float(c.y);
            ax = fmaf(nw2, fv.x, ax);
            ay = fmaf(nw2, fv.y, ay);
        }
        ax += __shfl_xor(ax, 32);
        ay += __shfl_xor(ay, 32);
        if (hw == 0) {
            if (ch0 < 47) out[(size_t)w * 47 + ch0] = ax + b0;
            if (ch1 < 47) out[(size_t)w * 47 + ch1] = ay + b1;
        }
    }
}

// ---------------------------------------------------------------------------
extern "C" void kernel_launch(void* const* d_in, const int* in_sizes, int n_in,
                              void* d_out, int out_size, void* d_ws, size_t ws_size,
                              hipStream_t stream) {
    const float* x  = (const float*)d_in[0];
    const void*  ei = d_in[1];
    const float* W1 = (const float*)d_in[3];
    const float* b1 = (const float*)d_in[4];
    const float* W2 = (const float*)d_in[5];
    const float* b2 = (const float*)d_in[6];
    const float* W3 = (const float*)d_in[7];
    const float* b3 = (const float*)d_in[8];
    float* out = (float*)d_out;

    size_t off = 0;
    auto alloc = [&](size_t bytes) -> void* {
        void* p = (char*)d_ws + off;
        off += (bytes + 511) & ~(size_t)511;
        return p;
    };
    float*  dis     = (float*)alloc((size_t)N_NODES * 4);
    int*    deg     = (int*)  alloc((size_t)N_NODES * 4);
    int*    rowst   = (int*)  alloc((size_t)N_NODES * 4);
    int*    bsize   = (int*)  alloc((NB + 1) * 4);
    int*    bbase   = (int*)  alloc((NB + 1) * 4);
    int*    bcur    = (int*)  alloc(NB * 4);
    int*    flag    = (int*)  alloc(64);
    int2*   csr_cn  = (int2*) alloc((size_t)N_EDGES * 8);
    __half* tbuf    = (__half*)alloc((size_t)N_NODES * 128 * 2);  // sliced t [8][N][16]
    __half* hbuf    = (__half*)alloc((size_t)N_NODES * 128 * 2);  // sliced act [8][N][16]
    // bucket planar arrays alias hbuf (12.8MB < 25.6MB; dead before gemm1 output use)
    int*    bktRow  = (int*)hbuf;
    int*    bktCol  = bktRow + N_EDGES;
    // layer-3 t rows [N][64] alias tbuf (tbuf dead after agg2 reads it)
    __half* t3      = tbuf;
    (void)ws_size; (void)in_sizes; (void)n_in; (void)out_size;

    int ptiles = (N_EDGES + PTILE - 1) / PTILE;   // 391

    // --- preprocessing ---
    detect_i64<<<1, 1024, 0, stream>>>((const int*)ei, flag, bsize);
    hist_buckets<<<ptiles, 256, 0, stream>>>(ei, flag, bsize);
    scan_buckets<<<1, 256, 0, stream>>>(bsize, bbase, bcur);
    partition_edges<<<ptiles, 256, 0, stream>>>(ei, flag, bcur, bktRow, bktCol);
    bucket_stats<<<NB, 512, 0, stream>>>(bktRow, bbase, deg, rowst, dis);
    scatter_bucket<<<NB, 512, 0, stream>>>(bktRow, bktCol, bbase, rowst, dis, csr_cn);

    int gblocks = (N_NODES + 63) / 64;   // 1563

    // --- layer 1 (fp32 in, sliced out) ---
    gemm_mfma<float, 8, false, true><<<gblocks, 256, 0, stream>>>(x, W1, tbuf, 128, 0);
    agg_c128_sl<<<2048, 256, 0, stream>>>(tbuf, rowst, deg, csr_cn, dis, b1, hbuf, 1);
    // --- layer 2 (sliced in, sliced out) ---
    gemm_mfma<_Float16, 8, true, true><<<gblocks, 256, 0, stream>>>(
        (_Float16*)hbuf, W2, tbuf, 128, 0);
    agg_c128_sl<<<2048, 256, 0, stream>>>(tbuf, rowst, deg, csr_cn, dis, b2, hbuf, 1);
    // --- layer 3 (sliced in, 47 cols, rows padded to 64 halves) ---
    gemm_mfma<_Float16, 3, true, false><<<gblocks, 256, 0, stream>>>(
        (_Float16*)hbuf, W3, t3, 47, 64);
    agg_c47<<<AGG_BLOCKS, 256, 0, stream>>>(t3, rowst, deg, csr_cn, dis, b3, out);
}

// Round 8
// 503.000 us; speedup vs baseline: 1.5367x; 1.5360x over previous
//
#include <hip/hip_runtime.h>
#include <hip/hip_fp16.h>
#include <cstdint>
#include <cstddef>

#define N_NODES 100000
#define N_EDGES 1600000
#define BSHIFT 9
#define BSIZE (1 << BSHIFT)
#define NB ((N_NODES + BSIZE - 1) >> BSHIFT)   // 196 buckets
#define PTILE 4096
#define BCAP 12288   // per-bucket capacity (mean 8192, std ~90 -> 22 sigma headroom)

typedef _Float16 half8 __attribute__((ext_vector_type(8)));
typedef float floatx4 __attribute__((ext_vector_type(4)));
typedef int v4i __attribute__((ext_vector_type(4)));

// CK-style raw buffer load intrinsic (compiler-scheduled, vmcnt-tracked).
// aux bit0 = sc0/glc: agent-scope load -> no L0 allocation, served from L2.
__device__ float llvm_amdgcn_raw_buffer_load_fp32(v4i srsrc, int voffset,
                                                  int soffset, int aux)
    __asm("llvm.amdgcn.raw.buffer.load.f32");

static __device__ __forceinline__ v4i make_srsrc(const void* p) {
    unsigned long long a = (unsigned long long)p;
    v4i r;
    r[0] = (int)(unsigned)(a & 0xFFFFFFFFull);
    r[1] = (int)(unsigned)((a >> 32) & 0xFFFFull);  // stride=0
    r[2] = -1;                                       // num_records: bounds off
    r[3] = 0x00020000;                               // raw dword access
    return r;
}

static __device__ __forceinline__ __half2 f_as_h2(float f) {
    union { float f; __half2 h; } u; u.f = f; return u.h;
}

// ---------------------------------------------------------------------------
// edge_index dtype handling (int64 vs int32 delivered by JAX)
// ---------------------------------------------------------------------------
static __device__ __forceinline__ int edge_row(const void* ei, int i64, int e) {
    return i64 ? (int)((const long long*)ei)[e] : ((const int*)ei)[e];
}
static __device__ __forceinline__ int edge_col(const void* ei, int i64, int e) {
    return i64 ? (int)((const long long*)ei)[N_EDGES + e] : ((const int*)ei)[N_EDGES + e];
}

// widened (1024 thr) + folds bucket-cursor init (bcur[b] = b*BCAP)
__global__ void __launch_bounds__(1024)
detect_i64(const int* __restrict__ w, int* __restrict__ flag,
           int* __restrict__ bcur) {
    __shared__ int red[1024];
    const int tid = threadIdx.x;
    if (tid < NB) bcur[tid] = tid * BCAP;
    int acc = 0;
    for (int j = tid; j < 2048; j += 1024) {
        int k = j * 781;
        acc |= w[2 * k + 1];
    }
    red[tid] = acc;
    __syncthreads();
    for (int off = 512; off > 0; off >>= 1) {
        if (tid < off) red[tid] |= red[tid + off];
        __syncthreads();
    }
    if (tid == 0) *flag = (red[0] == 0) ? 1 : 0;
}

// single-pass partition into fixed-capacity bucket regions [b*BCAP, ...)
// (replaces hist_buckets + pre-scan: cursors allocate directly)
__global__ void __launch_bounds__(256)
partition_edges(const void* __restrict__ ei, const int* __restrict__ flag,
                int* __restrict__ bcur, int* __restrict__ bktRow,
                int* __restrict__ bktCol) {
    __shared__ int rows[PTILE];
    __shared__ int cols[PTILE];
    __shared__ int h[256], sc[256], exs[256], base_s[256], p[256];

    const int tid = threadIdx.x;
    const int tbase = blockIdx.x * PTILE;
    const int tot = min(PTILE, N_EDGES - tbase);
    const int f = *flag;

    h[tid] = 0;
    p[tid] = 0;
    __syncthreads();

    #pragma unroll
    for (int j = 0; j < PTILE / 256; ++j) {
        int idx = tbase + tid + j * 256;
        if (idx < N_EDGES) {
            int r = edge_row(ei, f, idx);
            atomicAdd(&h[r >> BSHIFT], 1);
        }
    }
    __syncthreads();

    sc[tid] = h[tid];
    __syncthreads();
    for (int off = 1; off < 256; off <<= 1) {
        int v = (tid >= off) ? sc[tid - off] : 0;
        __syncthreads();
        sc[tid] += v;
        __syncthreads();
    }
    exs[tid] = sc[tid] - h[tid];
    if (tid < NB && h[tid] > 0) base_s[tid] = atomicAdd(&bcur[tid], h[tid]);
    __syncthreads();

    #pragma unroll
    for (int j = 0; j < PTILE / 256; ++j) {
        int idx = tbase + tid + j * 256;
        if (idx < N_EDGES) {
            int r = edge_row(ei, f, idx);
            int c = edge_col(ei, f, idx);
            int b = r >> BSHIFT;
            int lp = atomicAdd(&p[b], 1);
            int slot = exs[b] + lp;
            rows[slot] = r;
            cols[slot] = c;
        }
    }
    __syncthreads();

    for (int slot = tid; slot < tot; slot += 256) {
        int r = rows[slot];
        int b = r >> BSHIFT;
        int addr = base_s[b] + (slot - exs[b]);
        bktRow[addr] = r;
        bktCol[addr] = cols[slot];
    }
}

// exclusive scan of final bucket counts (bcur[b] - b*BCAP) -> bbase[NB+1]
__global__ void scan_buckets(const int* __restrict__ bcur, int* __restrict__ bbase) {
    __shared__ int sd[256];
    int t = threadIdx.x;
    int v = (t < NB) ? (bcur[t] - t * BCAP) : 0;
    sd[t] = v;
    __syncthreads();
    for (int off = 1; off < 256; off <<= 1) {
        int add = (t >= off) ? sd[t - off] : 0;
        __syncthreads();
        sd[t] += add;
        __syncthreads();
    }
    if (t < NB) bbase[t] = sd[t] - v;
    if (t == 255) bbase[NB] = sd[255];   // == N_EDGES
}

// per-bucket: degree histogram (LDS) + local scan -> deg, rowst (coalesced)
// compute_dis folded in. Bucket region = [b*BCAP, bcur[b]); CSR base = bbase[b].
__global__ void __launch_bounds__(512)
bucket_stats(const int* __restrict__ bktRow, const int* __restrict__ bcur,
             const int* __restrict__ bbase, int* __restrict__ deg,
             int* __restrict__ rowst, float* __restrict__ dis) {
    __shared__ int cnt[512];
    __shared__ int sd[512];
    const int b = blockIdx.x;
    const int t = threadIdx.x;
    const int start = b * BCAP, end = bcur[b];
    cnt[t] = 0;
    __syncthreads();
    for (int i = start + t; i < end; i += 512)
        atomicAdd(&cnt[bktRow[i] - (b << BSHIFT)], 1);
    __syncthreads();
    int v = cnt[t];
    sd[t] = v;
    __syncthreads();
    for (int off = 1; off < 512; off <<= 1) {
        int add = (t >= off) ? sd[t - off] : 0;
        __syncthreads();
        sd[t] += add;
        __syncthreads();
    }
    int node = (b << BSHIFT) + t;
    if (node < N_NODES) {
        deg[node] = v;
        rowst[node] = bbase[b] + sd[t] - v;
        dis[node] = rsqrtf((float)v + 1.0f);
    }
}

// per-bucket scatter to final CSR with LDS cursors; nrm computed here
__global__ void __launch_bounds__(512)
scatter_bucket(const int* __restrict__ bktRow, const int* __restrict__ bktCol,
               const int* __restrict__ bcur, const int* __restrict__ rowst,
               const float* __restrict__ dis, int2* __restrict__ csr_cn) {
    __shared__ int cur[512];
    __shared__ float dl[512];
    const int b = blockIdx.x;
    const int t = threadIdx.x;
    const int start = b * BCAP, end = bcur[b];
    int node = (b << BSHIFT) + t;
    cur[t] = (node < N_NODES) ? rowst[node] : 0;
    dl[t]  = (node < N_NODES) ? dis[node] : 0.f;
    __syncthreads();
    for (int i = start + t; i < end; i += 512) {
        int r = bktRow[i];
        int c = bktCol[i];
        int lr = r - (b << BSHIFT);
        int pos = atomicAdd(&cur[lr], 1);
        float nrm = dl[lr] * dis[c];
        csr_cn[pos] = make_int2(c, __float_as_int(nrm));
    }
}

// ---------------------------------------------------------------------------
// MFMA GEMM with XOR-swizzled LDS B tile (conflict-free b128 access).
// ostride: output row stride (64 for layer-3 padded rows, else Mfull).
// ---------------------------------------------------------------------------
template<typename TIn, int NT>
__global__ void __launch_bounds__(256)
gemm_mfma(const TIn* __restrict__ in, const float* __restrict__ W,
          __half* __restrict__ out, int Mfull, int ostride) {
    constexpr int NCOL = NT * 16;
    __shared__ _Float16 Wt[NCOL * 128];

    const int tid = threadIdx.x;
    for (int chunkIdx = tid; chunkIdx < NCOL * 16; chunkIdx += 256) {
        int n = chunkIdx % NCOL;
        int c = chunkIdx / NCOL;
        half8 v;
        #pragma unroll
        for (int i = 0; i < 8; ++i) {
            int k = c * 8 + i;
            v[i] = (n < Mfull) ? (_Float16)W[k * Mfull + n] : (_Float16)0.f;
        }
        *(half8*)&Wt[n * 128 + (c ^ (n & 7)) * 8] = v;
    }
    __syncthreads();

    const int wave = tid >> 6, lane = tid & 63;
    const int quad = lane >> 4, m = lane & 15;
    const int rowbase = blockIdx.x * 64 + wave * 16;
    const int arow_i = rowbase + m;
    const bool avalid = arow_i < N_NODES;
    const TIn* arow = in + (size_t)(avalid ? arow_i : 0) * 128;

    half8 a[4];
    #pragma unroll
    for (int kt = 0; kt < 4; ++kt) {
        if constexpr (sizeof(TIn) == 4) {
            const float4* ptr = (const float4*)((const float*)arow + kt * 32 + quad * 8);
            float4 f0 = ptr[0];
            float4 f1 = ptr[1];
            a[kt][0] = (_Float16)f0.x; a[kt][1] = (_Float16)f0.y;
            a[kt][2] = (_Float16)f0.z; a[kt][3] = (_Float16)f0.w;
            a[kt][4] = (_Float16)f1.x; a[kt][5] = (_Float16)f1.y;
            a[kt][6] = (_Float16)f1.z; a[kt][7] = (_Float16)f1.w;
        } else {
            a[kt] = *(const half8*)((const _Float16*)arow + kt * 32 + quad * 8);
        }
    }

    floatx4 acc[NT];
    #pragma unroll
    for (int ct = 0; ct < NT; ++ct) acc[ct] = (floatx4){0.f, 0.f, 0.f, 0.f};

    #pragma unroll
    for (int ct = 0; ct < NT; ++ct) {
        #pragma unroll
        for (int kt = 0; kt < 4; ++kt) {
            int n = ct * 16 + m;
            half8 bfrag = *(const half8*)&Wt[n * 128 + ((kt * 4 + quad) ^ (m & 7)) * 8];
            acc[ct] = __builtin_amdgcn_mfma_f32_16x16x32_f16(a[kt], bfrag, acc[ct], 0, 0, 0);
        }
    }

    const int rs0 = rowbase + quad * 4;
    #pragma unroll
    for (int ct = 0; ct < NT; ++ct) {
        int col = ct * 16 + m;
        if (col >= Mfull) continue;
        #pragma unroll
        for (int r = 0; r < 4; ++r) {
            int rs = rs0 + r;
            if (rs < N_NODES)
                out[(size_t)rs * ostride + col] = __float2half(acc[ct][r]);
        }
    }
}

// ---------------------------------------------------------------------------
// CSR aggregation over fp16 t rows, pipelined 6-wide, persistent waves.
// FROZEN at its measured memory-system roofline (70 µs across 5 structural
// variants; slicing alternative measured 3x worse).
// ---------------------------------------------------------------------------
#define AGG_DEPTH 6
#define AGG_BLOCKS 2048   // 8 blocks/CU; 8192 waves, ~12 rows each

__global__ void __launch_bounds__(256)
agg_c128(const __half* __restrict__ t, const int* __restrict__ rowst,
         const int* __restrict__ deg, const int2* __restrict__ cn,
         const float* __restrict__ dis, const float* __restrict__ bias,
         __half* __restrict__ out, int relu) {
    const int gwave = blockIdx.x * (blockDim.x >> 6) + (threadIdx.x >> 6);
    const int nw = gridDim.x * (blockDim.x >> 6);
    const int lane = threadIdx.x & 63;
    const float2 bv = ((const float2*)bias)[lane];   // invariant across rows
    const v4i trsrc = make_srsrc(t);
    const int voff_lane = lane << 2;                 // byte offset within row

    for (int w = gwave; w < N_NODES; w += nw) {
        int s = rowst[w], d = deg[w];
        float di = dis[w];
        float sn = di * di;
        float2 tv = __half22float2(((const __half2*)(t + (size_t)w * 128))[lane]);
        float ax = fmaf(sn, tv.x, bv.x);
        float ay = fmaf(sn, tv.y, bv.y);
        int e = s + d;
        int j = s;
        if (j + AGG_DEPTH <= e) {
            int2 c[AGG_DEPTH];
            #pragma unroll
            for (int q = 0; q < AGG_DEPTH; ++q) c[q] = cn[j + q];
            j += AGG_DEPTH;
            while (j + AGG_DEPTH <= e) {
                int2 n[AGG_DEPTH];
                #pragma unroll
                for (int q = 0; q < AGG_DEPTH; ++q) n[q] = cn[j + q];
                __half2 v[AGG_DEPTH];
                #pragma unroll
                for (int q = 0; q < AGG_DEPTH; ++q)
                    v[q] = f_as_h2(llvm_amdgcn_raw_buffer_load_fp32(
                        trsrc, (c[q].x << 8) | voff_lane, 0, 1));
                #pragma unroll
                for (int q = 0; q < AGG_DEPTH; ++q) {
                    float2 fv = __half22float2(v[q]);
                    float nw2 = __int_as_float(c[q].y);
                    ax = fmaf(nw2, fv.x, ax);
                    ay = fmaf(nw2, fv.y, ay);
                }
                #pragma unroll
                for (int q = 0; q < AGG_DEPTH; ++q) c[q] = n[q];
                j += AGG_DEPTH;
            }
            #pragma unroll
            for (int q = 0; q < AGG_DEPTH; ++q) {
                __half2 vv = f_as_h2(llvm_amdgcn_raw_buffer_load_fp32(
                    trsrc, (c[q].x << 8) | voff_lane, 0, 1));
                float2 fv = __half22float2(vv);
                float nw2 = __int_as_float(c[q].y);
                ax = fmaf(nw2, fv.x, ax);
                ay = fmaf(nw2, fv.y, ay);
            }
        }
        for (; j < e; ++j) {
            int2 c = cn[j];
            __half2 vv = f_as_h2(llvm_amdgcn_raw_buffer_load_fp32(
                trsrc, (c.x << 8) | voff_lane, 0, 1));
            float2 fv = __half22float2(vv);
            float nw2 = __int_as_float(c.y);
            ax = fmaf(nw2, fv.x, ax);
            ay = fmaf(nw2, fv.y, ay);
        }
        if (relu) { ax = fmaxf(ax, 0.f); ay = fmaxf(ay, 0.f); }
        ((__half2*)(out + (size_t)w * 128))[lane] = __float22half2_rn(make_float2(ax, ay));
    }
}

// ---------------------------------------------------------------------------
// agg_c47 (proven R5 version): t rows padded to 64 halves, dual-edge
// half-waves, rolling-4 pipeline, shfl_xor(32) combine.
// ---------------------------------------------------------------------------
#define C47_DEPTH 4

__global__ void __launch_bounds__(256)
agg_c47(const __half* __restrict__ t, const int* __restrict__ rowst,
        const int* __restrict__ deg, const int2* __restrict__ cn,
        const float* __restrict__ dis, const float* __restrict__ bias,
        float* __restrict__ out) {
    const int gwave = blockIdx.x * (blockDim.x >> 6) + (threadIdx.x >> 6);
    const int nw = gridDim.x * (blockDim.x >> 6);
    const int lane = threadIdx.x & 63;
    const int hw = lane >> 5;
    const int l2 = lane & 31;
    const int ch0 = l2 * 2, ch1 = ch0 + 1;
    const float b0 = (ch0 < 47) ? bias[ch0] : 0.f;
    const float b1 = (ch1 < 47) ? bias[ch1] : 0.f;

    for (int w = gwave; w < N_NODES; w += nw) {
        int s = rowst[w], d = deg[w];
        float di = dis[w];
        float sn = di * di;
        float2 tv = __half22float2(((const __half2*)(t + (size_t)w * 64))[l2]);
        float ax = (hw == 0) ? sn * tv.x : 0.f;
        float ay = (hw == 0) ? sn * tv.y : 0.f;
        int e = s + d;
        int j = s + hw;
        if (j + 2 * C47_DEPTH <= e + 1) {
            int2 c[C47_DEPTH];
            #pragma unroll
            for (int q = 0; q < C47_DEPTH; ++q) c[q] = cn[j + 2 * q];
            j += 2 * C47_DEPTH;
            while (j + 2 * C47_DEPTH <= e + 1) {
                int2 n[C47_DEPTH];
                #pragma unroll
                for (int q = 0; q < C47_DEPTH; ++q) n[q] = cn[j + 2 * q];
                __half2 v[C47_DEPTH];
                #pragma unroll
                for (int q = 0; q < C47_DEPTH; ++q)
                    v[q] = ((const __half2*)(t + (size_t)c[q].x * 64))[l2];
                #pragma unroll
                for (int q = 0; q < C47_DEPTH; ++q) {
                    float2 fv = __half22float2(v[q]);
                    float nw2 = __int_as_float(c[q].y);
                    ax = fmaf(nw2, fv.x, ax);
                    ay = fmaf(nw2, fv.y, ay);
                }
                #pragma unroll
                for (int q = 0; q < C47_DEPTH; ++q) c[q] = n[q];
                j += 2 * C47_DEPTH;
            }
            #pragma unroll
            for (int q = 0; q < C47_DEPTH; ++q) {
                __half2 vv = ((const __half2*)(t + (size_t)c[q].x * 64))[l2];
                float2 fv = __half22float2(vv);
                float nw2 = __int_as_float(c[q].y);
                ax = fmaf(nw2, fv.x, ax);
                ay = fmaf(nw2, fv.y, ay);
            }
        }
        for (; j < e; j += 2) {
            int2 c = cn[j];
            float2 fv = __half22float2(((const __half2*)(t + (size_t)c.x * 64))[l2]);
            float nw2 = __int_as_float(c.y);
            ax = fmaf(nw2, fv.x, ax);
            ay = fmaf(nw2, fv.y, ay);
        }
        ax += __shfl_xor(ax, 32);
        ay += __shfl_xor(ay, 32);
        if (hw == 0) {
            if (ch0 < 47) out[(size_t)w * 47 + ch0] = ax + b0;
            if (ch1 < 47) out[(size_t)w * 47 + ch1] = ay + b1;
        }
    }
}

// ---------------------------------------------------------------------------
extern "C" void kernel_launch(void* const* d_in, const int* in_sizes, int n_in,
                              void* d_out, int out_size, void* d_ws, size_t ws_size,
                              hipStream_t stream) {
    const float* x  = (const float*)d_in[0];
    const void*  ei = d_in[1];
    const float* W1 = (const float*)d_in[3];
    const float* b1 = (const float*)d_in[4];
    const float* W2 = (const float*)d_in[5];
    const float* b2 = (const float*)d_in[6];
    const float* W3 = (const float*)d_in[7];
    const float* b3 = (const float*)d_in[8];
    float* out = (float*)d_out;

    size_t off = 0;
    auto alloc = [&](size_t bytes) -> void* {
        void* p = (char*)d_ws + off;
        off += (bytes + 511) & ~(size_t)511;
        return p;
    };
    float*  dis     = (float*)alloc((size_t)N_NODES * 4);
    int*    deg     = (int*)  alloc((size_t)N_NODES * 4);
    int*    rowst   = (int*)  alloc((size_t)N_NODES * 4);
    int*    bbase   = (int*)  alloc((NB + 1) * 4);
    int*    bcur    = (int*)  alloc(NB * 4);
    int*    flag    = (int*)  alloc(64);
    int2*   csr_cn  = (int2*) alloc((size_t)N_EDGES * 8);
    __half* tbuf    = (__half*)alloc((size_t)N_NODES * 128 * 2);  // fp16 t rows
    __half* hbuf    = (__half*)alloc((size_t)N_NODES * 128 * 2);  // fp16 activations
    // fixed-capacity bucket regions alias hbuf (2 x 9.6MB < 25.6MB;
    // dead before gemm1's output (agg1 writes hbuf) is produced)
    int*    bktRow  = (int*)hbuf;
    int*    bktCol  = bktRow + (size_t)NB * BCAP;
    (void)ws_size; (void)in_sizes; (void)n_in; (void)out_size;

    int ptiles = (N_EDGES + PTILE - 1) / PTILE;   // 391

    // --- preprocessing: single-pass bucket build (no histogram pre-pass) ---
    detect_i64<<<1, 1024, 0, stream>>>((const int*)ei, flag, bcur);
    partition_edges<<<ptiles, 256, 0, stream>>>(ei, flag, bcur, bktRow, bktCol);
    scan_buckets<<<1, 256, 0, stream>>>(bcur, bbase);
    bucket_stats<<<NB, 512, 0, stream>>>(bktRow, bcur, bbase, deg, rowst, dis);
    scatter_bucket<<<NB, 512, 0, stream>>>(bktRow, bktCol, bcur, rowst, dis, csr_cn);

    int gblocks = (N_NODES + 63) / 64;   // 1563

    // --- layer 1 (fp32 in) ---
    gemm_mfma<float, 8><<<gblocks, 256, 0, stream>>>(x, W1, tbuf, 128, 128);
    agg_c128<<<AGG_BLOCKS, 256, 0, stream>>>(tbuf, rowst, deg, csr_cn, dis, b1, hbuf, 1);
    // --- layer 2 (fp16 in) ---
    gemm_mfma<_Float16, 8><<<gblocks, 256, 0, stream>>>((_Float16*)hbuf, W2, tbuf, 128, 128);
    agg_c128<<<AGG_BLOCKS, 256, 0, stream>>>(tbuf, rowst, deg, csr_cn, dis, b2, hbuf, 1);
    // --- layer 3 (fp16 in, 47 cols, rows padded to 64 halves = 128 B) ---
    gemm_mfma<_Float16, 3><<<gblocks, 256, 0, stream>>>((_Float16*)hbuf, W3, tbuf, 47, 64);
    agg_c47<<<AGG_BLOCKS, 256, 0, stream>>>(tbuf, rowst, deg, csr_cn, dis, b3, out);
}

// Round 9
// 496.042 us; speedup vs baseline: 1.5582x; 1.0140x over previous
//
#include <hip/hip_runtime.h>
#include <hip/hip_fp16.h>
#include <cstdint>
#include <cstddef>

#define N_NODES 100000
#define N_EDGES 1600000
#define BSHIFT 9
#define BSIZE (1 << BSHIFT)
#define NB ((N_NODES + BSIZE - 1) >> BSHIFT)   // 196 buckets
#define PTILE 4096

typedef _Float16 half8 __attribute__((ext_vector_type(8)));
typedef float floatx4 __attribute__((ext_vector_type(4)));
typedef int v4i __attribute__((ext_vector_type(4)));

// CK-style raw buffer load intrinsic (compiler-scheduled, vmcnt-tracked).
// aux bit0 = sc0/glc: agent-scope load -> no L0 allocation, served from L2.
__device__ float llvm_amdgcn_raw_buffer_load_fp32(v4i srsrc, int voffset,
                                                  int soffset, int aux)
    __asm("llvm.amdgcn.raw.buffer.load.f32");

static __device__ __forceinline__ v4i make_srsrc(const void* p) {
    unsigned long long a = (unsigned long long)p;
    v4i r;
    r[0] = (int)(unsigned)(a & 0xFFFFFFFFull);
    r[1] = (int)(unsigned)((a >> 32) & 0xFFFFull);  // stride=0
    r[2] = -1;                                       // num_records: bounds off
    r[3] = 0x00020000;                               // raw dword access
    return r;
}

static __device__ __forceinline__ __half2 f_as_h2(float f) {
    union { float f; __half2 h; } u; u.f = f; return u.h;
}

// ---------------------------------------------------------------------------
// edge_index dtype handling (int64 vs int32 delivered by JAX)
// ---------------------------------------------------------------------------
static __device__ __forceinline__ int edge_row(const void* ei, int i64, int e) {
    return i64 ? (int)((const long long*)ei)[e] : ((const int*)ei)[e];
}
static __device__ __forceinline__ int edge_col(const void* ei, int i64, int e) {
    return i64 ? (int)((const long long*)ei)[N_EDGES + e] : ((const int*)ei)[N_EDGES + e];
}

// widened (1024 thr, 2 latency rounds instead of 8) + folds bsize zeroing
__global__ void __launch_bounds__(1024)
detect_i64(const int* __restrict__ w, int* __restrict__ flag,
           int* __restrict__ bsize) {
    __shared__ int red[1024];
    const int tid = threadIdx.x;
    if (tid < NB + 1) bsize[tid] = 0;
    int acc = 0;
    for (int j = tid; j < 2048; j += 1024) {
        int k = j * 781;
        acc |= w[2 * k + 1];
    }
    red[tid] = acc;
    __syncthreads();
    for (int off = 512; off > 0; off >>= 1) {
        if (tid < off) red[tid] |= red[tid + off];
        __syncthreads();
    }
    if (tid == 0) *flag = (red[0] == 0) ? 1 : 0;
}

// per-tile LDS histogram of buckets -> few global atomics (196/block)
__global__ void __launch_bounds__(256)
hist_buckets(const void* __restrict__ ei, const int* __restrict__ flag,
             int* __restrict__ bsize) {
    __shared__ int h[256];
    const int tid = threadIdx.x;
    const int tbase = blockIdx.x * PTILE;
    const int f = *flag;
    h[tid] = 0;
    __syncthreads();
    #pragma unroll
    for (int j = 0; j < PTILE / 256; ++j) {
        int idx = tbase + tid + j * 256;
        if (idx < N_EDGES) {
            int r = edge_row(ei, f, idx);
            atomicAdd(&h[r >> BSHIFT], 1);
        }
    }
    __syncthreads();
    if (tid < NB && h[tid] > 0) atomicAdd(&bsize[tid], h[tid]);
}

// exclusive scan of bucket sizes -> bbase[NB+1], bcur
__global__ void scan_buckets(const int* __restrict__ bsize, int* __restrict__ bbase,
                             int* __restrict__ bcur) {
    __shared__ int sd[256];
    int t = threadIdx.x;
    int v = (t < NB) ? bsize[t] : 0;
    sd[t] = v;
    __syncthreads();
    for (int off = 1; off < 256; off <<= 1) {
        int add = (t >= off) ? sd[t - off] : 0;
        __syncthreads();
        sd[t] += add;
        __syncthreads();
    }
    if (t < NB) {
        bbase[t] = sd[t] - v;
        bcur[t] = sd[t] - v;
    }
    if (t == 255) bbase[NB] = sd[255];   // == N_EDGES
}

// partition edges into buckets (rows+cols planar, coalesced flush)
__global__ void __launch_bounds__(256)
partition_edges(const void* __restrict__ ei, const int* __restrict__ flag,
                int* __restrict__ bcur, int* __restrict__ bktRow,
                int* __restrict__ bktCol) {
    __shared__ int rows[PTILE];
    __shared__ int cols[PTILE];
    __shared__ int h[256], sc[256], exs[256], base_s[256], p[256];

    const int tid = threadIdx.x;
    const int tbase = blockIdx.x * PTILE;
    const int tot = min(PTILE, N_EDGES - tbase);
    const int f = *flag;

    h[tid] = 0;
    p[tid] = 0;
    __syncthreads();

    #pragma unroll
    for (int j = 0; j < PTILE / 256; ++j) {
        int idx = tbase + tid + j * 256;
        if (idx < N_EDGES) {
            int r = edge_row(ei, f, idx);
            atomicAdd(&h[r >> BSHIFT], 1);
        }
    }
    __syncthreads();

    sc[tid] = h[tid];
    __syncthreads();
    for (int off = 1; off < 256; off <<= 1) {
        int v = (tid >= off) ? sc[tid - off] : 0;
        __syncthreads();
        sc[tid] += v;
        __syncthreads();
    }
    exs[tid] = sc[tid] - h[tid];
    if (tid < NB && h[tid] > 0) base_s[tid] = atomicAdd(&bcur[tid], h[tid]);
    __syncthreads();

    #pragma unroll
    for (int j = 0; j < PTILE / 256; ++j) {
        int idx = tbase + tid + j * 256;
        if (idx < N_EDGES) {
            int r = edge_row(ei, f, idx);
            int c = edge_col(ei, f, idx);
            int b = r >> BSHIFT;
            int lp = atomicAdd(&p[b], 1);
            int slot = exs[b] + lp;
            rows[slot] = r;
            cols[slot] = c;
        }
    }
    __syncthreads();

    for (int slot = tid; slot < tot; slot += 256) {
        int r = rows[slot];
        int b = r >> BSHIFT;
        int addr = base_s[b] + (slot - exs[b]);
        bktRow[addr] = r;
        bktCol[addr] = cols[slot];
    }
}

// per-bucket: degree histogram (LDS) + local scan -> deg, rowst (coalesced)
// compute_dis folded in.
__global__ void __launch_bounds__(512)
bucket_stats(const int* __restrict__ bktRow, const int* __restrict__ bbase,
             int* __restrict__ deg, int* __restrict__ rowst,
             float* __restrict__ dis) {
    __shared__ int cnt[512];
    __shared__ int sd[512];
    const int b = blockIdx.x;
    const int t = threadIdx.x;
    const int start = bbase[b], end = bbase[b + 1];
    cnt[t] = 0;
    __syncthreads();
    for (int i = start + t; i < end; i += 512)
        atomicAdd(&cnt[bktRow[i] - (b << BSHIFT)], 1);
    __syncthreads();
    int v = cnt[t];
    sd[t] = v;
    __syncthreads();
    for (int off = 1; off < 512; off <<= 1) {
        int add = (t >= off) ? sd[t - off] : 0;
        __syncthreads();
        sd[t] += add;
        __syncthreads();
    }
    int node = (b << BSHIFT) + t;
    if (node < N_NODES) {
        deg[node] = v;
        rowst[node] = start + sd[t] - v;
        dis[node] = rsqrtf((float)v + 1.0f);
    }
}

// per-bucket scatter to final CSR with LDS cursors; nrm computed here
__global__ void __launch_bounds__(512)
scatter_bucket(const int* __restrict__ bktRow, const int* __restrict__ bktCol,
               const int* __restrict__ bbase, const int* __restrict__ rowst,
               const float* __restrict__ dis, int2* __restrict__ csr_cn) {
    __shared__ int cur[512];
    __shared__ float dl[512];
    const int b = blockIdx.x;
    const int t = threadIdx.x;
    const int start = bbase[b], end = bbase[b + 1];
    int node = (b << BSHIFT) + t;
    cur[t] = (node < N_NODES) ? rowst[node] : 0;
    dl[t]  = (node < N_NODES) ? dis[node] : 0.f;
    __syncthreads();
    for (int i = start + t; i < end; i += 512) {
        int r = bktRow[i];
        int c = bktCol[i];
        int lr = r - (b << BSHIFT);
        int pos = atomicAdd(&cur[lr], 1);
        float nrm = dl[lr] * dis[c];
        csr_cn[pos] = make_int2(c, __float_as_int(nrm));
    }
}

// ---------------------------------------------------------------------------
// MFMA GEMM with XOR-swizzled LDS B tile (conflict-free b128 access).
// ostride: output row stride (64 for layer-3 padded rows, else Mfull).
// ---------------------------------------------------------------------------
template<typename TIn, int NT>
__global__ void __launch_bounds__(256)
gemm_mfma(const TIn* __restrict__ in, const float* __restrict__ W,
          __half* __restrict__ out, int Mfull, int ostride) {
    constexpr int NCOL = NT * 16;
    __shared__ _Float16 Wt[NCOL * 128];

    const int tid = threadIdx.x;
    for (int chunkIdx = tid; chunkIdx < NCOL * 16; chunkIdx += 256) {
        int n = chunkIdx % NCOL;
        int c = chunkIdx / NCOL;
        half8 v;
        #pragma unroll
        for (int i = 0; i < 8; ++i) {
            int k = c * 8 + i;
            v[i] = (n < Mfull) ? (_Float16)W[k * Mfull + n] : (_Float16)0.f;
        }
        *(half8*)&Wt[n * 128 + (c ^ (n & 7)) * 8] = v;
    }
    __syncthreads();

    const int wave = tid >> 6, lane = tid & 63;
    const int quad = lane >> 4, m = lane & 15;
    const int rowbase = blockIdx.x * 64 + wave * 16;
    const int arow_i = rowbase + m;
    const bool avalid = arow_i < N_NODES;
    const TIn* arow = in + (size_t)(avalid ? arow_i : 0) * 128;

    half8 a[4];
    #pragma unroll
    for (int kt = 0; kt < 4; ++kt) {
        if constexpr (sizeof(TIn) == 4) {
            const float4* ptr = (const float4*)((const float*)arow + kt * 32 + quad * 8);
            float4 f0 = ptr[0];
            float4 f1 = ptr[1];
            a[kt][0] = (_Float16)f0.x; a[kt][1] = (_Float16)f0.y;
            a[kt][2] = (_Float16)f0.z; a[kt][3] = (_Float16)f0.w;
            a[kt][4] = (_Float16)f1.x; a[kt][5] = (_Float16)f1.y;
            a[kt][6] = (_Float16)f1.z; a[kt][7] = (_Float16)f1.w;
        } else {
            a[kt] = *(const half8*)((const _Float16*)arow + kt * 32 + quad * 8);
        }
    }

    floatx4 acc[NT];
    #pragma unroll
    for (int ct = 0; ct < NT; ++ct) acc[ct] = (floatx4){0.f, 0.f, 0.f, 0.f};

    #pragma unroll
    for (int ct = 0; ct < NT; ++ct) {
        #pragma unroll
        for (int kt = 0; kt < 4; ++kt) {
            int n = ct * 16 + m;
            half8 bfrag = *(const half8*)&Wt[n * 128 + ((kt * 4 + quad) ^ (m & 7)) * 8];
            acc[ct] = __builtin_amdgcn_mfma_f32_16x16x32_f16(a[kt], bfrag, acc[ct], 0, 0, 0);
        }
    }

    const int rs0 = rowbase + quad * 4;
    #pragma unroll
    for (int ct = 0; ct < NT; ++ct) {
        int col = ct * 16 + m;
        if (col >= Mfull) continue;
        #pragma unroll
        for (int r = 0; r < 4; ++r) {
            int rs = rs0 + r;
            if (rs < N_NODES)
                out[(size_t)rs * ostride + col] = __float2half(acc[ct][r]);
        }
    }
}

// ---------------------------------------------------------------------------
// CSR aggregation over fp16 t rows, pipelined 6-wide, persistent waves.
// FROZEN at its measured memory-system roofline: 70 µs across 5 structural
// variants (depth-6 / flat-12 / persistent / sc0 / +MLP); locality
// counter-experiment (XCD slicing) cut FETCH 200->84 MB but ran 3x slower.
// ---------------------------------------------------------------------------
#define AGG_DEPTH 6
#define AGG_BLOCKS 2048   // 8 blocks/CU; 8192 waves, ~12 rows each

__global__ void __launch_bounds__(256)
agg_c128(const __half* __restrict__ t, const int* __restrict__ rowst,
         const int* __restrict__ deg, const int2* __restrict__ cn,
         const float* __restrict__ dis, const float* __restrict__ bias,
         __half* __restrict__ out, int relu) {
    const int gwave = blockIdx.x * (blockDim.x >> 6) + (threadIdx.x >> 6);
    const int nw = gridDim.x * (blockDim.x >> 6);
    const int lane = threadIdx.x & 63;
    const float2 bv = ((const float2*)bias)[lane];   // invariant across rows
    const v4i trsrc = make_srsrc(t);
    const int voff_lane = lane << 2;                 // byte offset within row

    for (int w = gwave; w < N_NODES; w += nw) {
        int s = rowst[w], d = deg[w];
        float di = dis[w];
        float sn = di * di;
        float2 tv = __half22float2(((const __half2*)(t + (size_t)w * 128))[lane]);
        float ax = fmaf(sn, tv.x, bv.x);
        float ay = fmaf(sn, tv.y, bv.y);
        int e = s + d;
        int j = s;
        if (j + AGG_DEPTH <= e) {
            int2 c[AGG_DEPTH];
            #pragma unroll
            for (int q = 0; q < AGG_DEPTH; ++q) c[q] = cn[j + q];
            j += AGG_DEPTH;
            while (j + AGG_DEPTH <= e) {
                int2 n[AGG_DEPTH];
                #pragma unroll
                for (int q = 0; q < AGG_DEPTH; ++q) n[q] = cn[j + q];
                __half2 v[AGG_DEPTH];
                #pragma unroll
                for (int q = 0; q < AGG_DEPTH; ++q)
                    v[q] = f_as_h2(llvm_amdgcn_raw_buffer_load_fp32(
                        trsrc, (c[q].x << 8) | voff_lane, 0, 1));
                #pragma unroll
                for (int q = 0; q < AGG_DEPTH; ++q) {
                    float2 fv = __half22float2(v[q]);
                    float nw2 = __int_as_float(c[q].y);
                    ax = fmaf(nw2, fv.x, ax);
                    ay = fmaf(nw2, fv.y, ay);
                }
                #pragma unroll
                for (int q = 0; q < AGG_DEPTH; ++q) c[q] = n[q];
                j += AGG_DEPTH;
            }
            #pragma unroll
            for (int q = 0; q < AGG_DEPTH; ++q) {
                __half2 vv = f_as_h2(llvm_amdgcn_raw_buffer_load_fp32(
                    trsrc, (c[q].x << 8) | voff_lane, 0, 1));
                float2 fv = __half22float2(vv);
                float nw2 = __int_as_float(c[q].y);
                ax = fmaf(nw2, fv.x, ax);
                ay = fmaf(nw2, fv.y, ay);
            }
        }
        for (; j < e; ++j) {
            int2 c = cn[j];
            __half2 vv = f_as_h2(llvm_amdgcn_raw_buffer_load_fp32(
                trsrc, (c.x << 8) | voff_lane, 0, 1));
            float2 fv = __half22float2(vv);
            float nw2 = __int_as_float(c.y);
            ax = fmaf(nw2, fv.x, ax);
            ay = fmaf(nw2, fv.y, ay);
        }
        if (relu) { ax = fmaxf(ax, 0.f); ay = fmaxf(ay, 0.f); }
        ((__half2*)(out + (size_t)w * 128))[lane] = __float22half2_rn(make_float2(ax, ay));
    }
}

// ---------------------------------------------------------------------------
// agg_c47: t rows padded to 64 halves (128 B, line-aligned — no straddle
// waste). Dual-edge half-waves, rolling-4 pipeline, shfl_xor(32) combine.
// ---------------------------------------------------------------------------
#define C47_DEPTH 4

__global__ void __launch_bounds__(256)
agg_c47(const __half* __restrict__ t, const int* __restrict__ rowst,
        const int* __restrict__ deg, const int2* __restrict__ cn,
        const float* __restrict__ dis, const float* __restrict__ bias,
        float* __restrict__ out) {
    const int gwave = blockIdx.x * (blockDim.x >> 6) + (threadIdx.x >> 6);
    const int nw = gridDim.x * (blockDim.x >> 6);
    const int lane = threadIdx.x & 63;
    const int hw = lane >> 5;            // half-wave id (edge parity)
    const int l2 = lane & 31;            // lane within half-wave
    const int ch0 = l2 * 2, ch1 = ch0 + 1;
    const float b0 = (ch0 < 47) ? bias[ch0] : 0.f;
    const float b1 = (ch1 < 47) ? bias[ch1] : 0.f;

    for (int w = gwave; w < N_NODES; w += nw) {
        int s = rowst[w], d = deg[w];
        float di = dis[w];
        float sn = di * di;
        float2 tv = __half22float2(((const __half2*)(t + (size_t)w * 64))[l2]);
        float ax = (hw == 0) ? sn * tv.x : 0.f;
        float ay = (hw == 0) ? sn * tv.y : 0.f;
        int e = s + d;
        int j = s + hw;                  // this half-wave's edges: j, j+2, ...
        if (j + 2 * C47_DEPTH <= e + 1) {
            int2 c[C47_DEPTH];
            #pragma unroll
            for (int q = 0; q < C47_DEPTH; ++q) c[q] = cn[j + 2 * q];
            j += 2 * C47_DEPTH;
            while (j + 2 * C47_DEPTH <= e + 1) {
                int2 n[C47_DEPTH];
                #pragma unroll
                for (int q = 0; q < C47_DEPTH; ++q) n[q] = cn[j + 2 * q];
                __half2 v[C47_DEPTH];
                #pragma unroll
                for (int q = 0; q < C47_DEPTH; ++q)
                    v[q] = ((const __half2*)(t + (size_t)c[q].x * 64))[l2];
                #pragma unroll
                for (int q = 0; q < C47_DEPTH; ++q) {
                    float2 fv = __half22float2(v[q]);
                    float nw2 = __int_as_float(c[q].y);
                    ax = fmaf(nw2, fv.x, ax);
                    ay = fmaf(nw2, fv.y, ay);
                }
                #pragma unroll
                for (int q = 0; q < C47_DEPTH; ++q) c[q] = n[q];
                j += 2 * C47_DEPTH;
            }
            #pragma unroll
            for (int q = 0; q < C47_DEPTH; ++q) {
                __half2 vv = ((const __half2*)(t + (size_t)c[q].x * 64))[l2];
                float2 fv = __half22float2(vv);
                float nw2 = __int_as_float(c[q].y);
                ax = fmaf(nw2, fv.x, ax);
                ay = fmaf(nw2, fv.y, ay);
            }
        }
        for (; j < e; j += 2) {
            int2 c = cn[j];
            float2 fv = __half22float2(((const __half2*)(t + (size_t)c.x * 64))[l2]);
            float nw2 = __int_as_float(c.y);
            ax = fmaf(nw2, fv.x, ax);
            ay = fmaf(nw2, fv.y, ay);
        }
        ax += __shfl_xor(ax, 32);
        ay += __shfl_xor(ay, 32);
        if (hw == 0) {
            if (ch0 < 47) out[(size_t)w * 47 + ch0] = ax + b0;
            if (ch1 < 47) out[(size_t)w * 47 + ch1] = ay + b1;
        }
    }
}

// ---------------------------------------------------------------------------
extern "C" void kernel_launch(void* const* d_in, const int* in_sizes, int n_in,
                              void* d_out, int out_size, void* d_ws, size_t ws_size,
                              hipStream_t stream) {
    const float* x  = (const float*)d_in[0];
    const void*  ei = d_in[1];
    const float* W1 = (const float*)d_in[3];
    const float* b1 = (const float*)d_in[4];
    const float* W2 = (const float*)d_in[5];
    const float* b2 = (const float*)d_in[6];
    const float* W3 = (const float*)d_in[7];
    const float* b3 = (const float*)d_in[8];
    float* out = (float*)d_out;

    size_t off = 0;
    auto alloc = [&](size_t bytes) -> void* {
        void* p = (char*)d_ws + off;
        off += (bytes + 511) & ~(size_t)511;
        return p;
    };
    float*  dis     = (float*)alloc((size_t)N_NODES * 4);
    int*    deg     = (int*)  alloc((size_t)N_NODES * 4);
    int*    rowst   = (int*)  alloc((size_t)N_NODES * 4);
    int*    bsize   = (int*)  alloc((NB + 1) * 4);
    int*    bbase   = (int*)  alloc((NB + 1) * 4);
    int*    bcur    = (int*)  alloc(NB * 4);
    int*    flag    = (int*)  alloc(64);
    int2*   csr_cn  = (int2*) alloc((size_t)N_EDGES * 8);
    __half* tbuf    = (__half*)alloc((size_t)N_NODES * 128 * 2);  // fp16 t rows
    __half* hbuf    = (__half*)alloc((size_t)N_NODES * 128 * 2);  // fp16 activations
    // bucket planar arrays alias hbuf (12.8MB < 25.6MB; dead before gemm1 output use)
    int*    bktRow  = (int*)hbuf;
    int*    bktCol  = bktRow + N_EDGES;
    (void)ws_size; (void)in_sizes; (void)n_in; (void)out_size;

    int ptiles = (N_EDGES + PTILE - 1) / PTILE;   // 391

    // --- preprocessing: no random global atomics ---
    detect_i64<<<1, 1024, 0, stream>>>((const int*)ei, flag, bsize);
    hist_buckets<<<ptiles, 256, 0, stream>>>(ei, flag, bsize);
    scan_buckets<<<1, 256, 0, stream>>>(bsize, bbase, bcur);
    partition_edges<<<ptiles, 256, 0, stream>>>(ei, flag, bcur, bktRow, bktCol);
    bucket_stats<<<NB, 512, 0, stream>>>(bktRow, bbase, deg, rowst, dis);
    scatter_bucket<<<NB, 512, 0, stream>>>(bktRow, bktCol, bbase, rowst, dis, csr_cn);

    int gblocks = (N_NODES + 63) / 64;   // 1563

    // --- layer 1 (fp32 in) ---
    gemm_mfma<float, 8><<<gblocks, 256, 0, stream>>>(x, W1, tbuf, 128, 128);
    agg_c128<<<AGG_BLOCKS, 256, 0, stream>>>(tbuf, rowst, deg, csr_cn, dis, b1, hbuf, 1);
    // --- layer 2 (fp16 in) ---
    gemm_mfma<_Float16, 8><<<gblocks, 256, 0, stream>>>((_Float16*)hbuf, W2, tbuf, 128, 128);
    agg_c128<<<AGG_BLOCKS, 256, 0, stream>>>(tbuf, rowst, deg, csr_cn, dis, b2, hbuf, 1);
    // --- layer 3 (fp16 in, 47 cols, rows padded to 64 halves = 128 B) ---
    gemm_mfma<_Float16, 3><<<gblocks, 256, 0, stream>>>((_Float16*)hbuf, W3, tbuf, 47, 64);
    agg_c47<<<AGG_BLOCKS, 256, 0, stream>>>(tbuf, rowst, deg, csr_cn, dis, b3, out);
}